// Round 5
// baseline (117.254 us; speedup 1.0000x reference)
//
#include <hip/hip_runtime.h>
#include <math.h>

// Problem constants (fixed by the reference's setup_inputs)
#define T_STEPS 16
#define BB      128
#define VOCAB   32000
#define HALF_V  (VOCAB / 2)   // 16000 words per half-row
#define V4H     (HALF_V / 4)  // 4000 float4 per half-row
#define BEAM    4
#define BATCH   (BB / BEAM)   // 32
#define TAU     2.75f         // survivor threshold: E[survivors/half] ~ 48

// ---------------------------------------------------------------------------
// Total-order comparator matching jax.lax.top_k: value descending, index
// ascending on ties. (a ranks before b)?
__device__ __forceinline__ bool gtvi(float av, int ai, float bv, int bi) {
    return (av > bv) || (av == bv && ai < bi);
}

// Insert (x, gi) into a sorted-descending top-8 list held in registers.
__device__ __forceinline__ void ins8(float (&v)[8], int (&ix)[8], float x, int gi) {
    if (gtvi(x, gi, v[7], ix[7])) {
        v[7] = x; ix[7] = gi;
#pragma unroll
        for (int j = 7; j > 0; --j) {
            if (gtvi(v[j], ix[j], v[j - 1], ix[j - 1])) {
                float tv = v[j]; v[j] = v[j - 1]; v[j - 1] = tv;
                int   ti = ix[j]; ix[j] = ix[j - 1]; ix[j - 1] = ti;
            }
        }
    }
}

// Wave(64)-level butterfly merge of per-lane sorted-desc 8-lists.
__device__ __forceinline__ void wave_merge8(float (&v)[8], int (&ix)[8]) {
#pragma unroll
    for (int m = 1; m < 64; m <<= 1) {
        float u[8]; int ju[8];
#pragma unroll
        for (int k = 0; k < 8; ++k) {
            u[k]  = __shfl_xor(v[k],  m, 64);
            ju[k] = __shfl_xor(ix[k], m, 64);
        }
        float w[8]; int jw[8];
#pragma unroll
        for (int k = 0; k < 8; ++k) {
            if (gtvi(u[7 - k], ju[7 - k], v[k], ix[k])) { w[k] = u[7 - k]; jw[k] = ju[7 - k]; }
            else                                        { w[k] = v[k];     jw[k] = ix[k];     }
        }
#define CE_DESC(a, b)                                                         \
        if (gtvi(w[b], jw[b], w[a], jw[a])) {                                 \
            float tv = w[a]; w[a] = w[b]; w[b] = tv;                          \
            int   ti = jw[a]; jw[a] = jw[b]; jw[b] = ti;                      \
        }
        CE_DESC(0, 4) CE_DESC(1, 5) CE_DESC(2, 6) CE_DESC(3, 7)
        CE_DESC(0, 2) CE_DESC(1, 3) CE_DESC(4, 6) CE_DESC(5, 7)
        CE_DESC(0, 1) CE_DESC(2, 3) CE_DESC(4, 5) CE_DESC(6, 7)
#undef CE_DESC
#pragma unroll
        for (int k = 0; k < 8; ++k) { v[k] = w[k]; ix[k] = jw[k]; }
    }
}

// ---------------------------------------------------------------------------
// Phase 1: one block per HALF-row. Computes the half's partial sum(exp(x))
// and its exact top-8 of x (excluding pad/unk), writing RAW logit values
// (log-softmax normalization is applied in phase 2 after combining halves).
// Hot loop: zero LDS, depth-4 software pipeline (4 loads in flight/thread).
__global__ __launch_bounds__(256, 4) void phase1_topk_half(
    const float* __restrict__ logits,
    const int*   __restrict__ pad_p,
    const int*   __restrict__ unk_p,
    float* __restrict__ topv,   // [T*BB*2 * 8] raw top values per half
    int*   __restrict__ topi,   // [T*BB*2 * 8] word indices per half
    float* __restrict__ sums)   // [T*BB*2]     partial exp-sums per half
{
    __shared__ float s_red[4];
    __shared__ int   s_icnt[4];
    __shared__ float s_mv[32];
    __shared__ int   s_mi[32];
    __shared__ int   s_tot;

    const int hrow = blockIdx.x;           // (t*BB + r)*2 + h
    const int h    = hrow & 1;
    const int row  = hrow >> 1;
    const int tid  = threadIdx.x;
    const int pad  = *pad_p, unk = *unk_p;
    const int hbase = h * HALF_V;          // global word offset of this half
    const float4* __restrict__ src =
        reinterpret_cast<const float4*>(logits + (size_t)row * VOCAB + hbase);

    float v[8]; int ix[8];
#pragma unroll
    for (int k = 0; k < 8; ++k) { v[k] = -INFINITY; ix[k] = 0x7FFFFFFF; }
    float tsum = 0.0f;
    int   scnt = 0;

    auto process = [&](float4 q, int gi) {   // gi = global word index of q.x
        tsum += (__expf(q.x) + __expf(q.y)) + (__expf(q.z) + __expf(q.w));
        const float mx = fmaxf(fmaxf(q.x, q.y), fmaxf(q.z, q.w));
        if (mx > TAU) {
            if (q.x > TAU) { if ((gi + 0) != pad && (gi + 0) != unk) { ins8(v, ix, q.x, gi + 0); ++scnt; } }
            if (q.y > TAU) { if ((gi + 1) != pad && (gi + 1) != unk) { ins8(v, ix, q.y, gi + 1); ++scnt; } }
            if (q.z > TAU) { if ((gi + 2) != pad && (gi + 2) != unk) { ins8(v, ix, q.z, gi + 2); ++scnt; } }
            if (q.w > TAU) { if ((gi + 3) != pad && (gi + 3) != unk) { ins8(v, ix, q.w, gi + 3); ++scnt; } }
        }
    };

    // ---- depth-4 pipelined hot loop over 15 strided iters + 160-thread tail
    // kv = tid + 256*i for i=0..14 (max 3839), then 3840+tid for tid<160.
    int kv = tid;
    float4 b0 = src[kv];
    float4 b1 = src[kv + 256];
    float4 b2 = src[kv + 512];
    float4 b3 = src[kv + 768];
    for (int c = 0; c < 2; ++c) {          // processes i=0..7, prefetch i=4..11
        float4 n0 = src[kv + 1024];
        float4 n1 = src[kv + 1280];
        float4 n2 = src[kv + 1536];
        float4 n3 = src[kv + 1792];
        process(b0, hbase + kv * 4);
        process(b1, hbase + (kv + 256) * 4);
        process(b2, hbase + (kv + 512) * 4);
        process(b3, hbase + (kv + 768) * 4);
        b0 = n0; b1 = n1; b2 = n2; b3 = n3;
        kv += 1024;
    }
    // kv = tid + 2048; b0..b3 hold i=8..11; prefetch i=12..14 + tail
    float4 n0 = src[kv + 1024];            // i=12
    float4 n1 = src[kv + 1280];            // i=13
    float4 n2 = src[kv + 1536];            // i=14 (max 3839)
    float4 tq;
    const bool ht = (tid < 160);
    if (ht) tq = src[3840 + tid];
    process(b0, hbase + kv * 4);
    process(b1, hbase + (kv + 256) * 4);
    process(b2, hbase + (kv + 512) * 4);
    process(b3, hbase + (kv + 768) * 4);
    process(n0, hbase + (kv + 1024) * 4);
    process(n1, hbase + (kv + 1280) * 4);
    process(n2, hbase + (kv + 1536) * 4);
    if (ht) process(tq, hbase + (3840 + tid) * 4);

    // ---- block reductions: partial exp-sum and survivor count ----
#pragma unroll
    for (int m = 1; m < 64; m <<= 1) {
        tsum += __shfl_xor(tsum, m, 64);
        scnt += __shfl_xor(scnt, m, 64);
    }
    const int wv = tid >> 6, ln = tid & 63;
    if (ln == 0) { s_red[wv] = tsum; s_icnt[wv] = scnt; }
    __syncthreads();
    if (tid == 0) {
        sums[hrow] = (s_red[0] + s_red[1]) + (s_red[2] + s_red[3]);
        s_tot      = (s_icnt[0] + s_icnt[1]) + (s_icnt[2] + s_icnt[3]);
    }
    __syncthreads();

    if (s_tot < 8) {
        // ---- exact fallback (never for N(0,1) rows): rescan this half ----
#pragma unroll
        for (int k = 0; k < 8; ++k) { v[k] = -INFINITY; ix[k] = 0x7FFFFFFF; }
        for (int k2 = tid; k2 < V4H; k2 += 256) {
            float4 f = src[k2];
            const int gi = hbase + k2 * 4;
            if ((gi + 0) != pad && (gi + 0) != unk) ins8(v, ix, f.x, gi + 0);
            if ((gi + 1) != pad && (gi + 1) != unk) ins8(v, ix, f.y, gi + 1);
            if ((gi + 2) != pad && (gi + 2) != unk) ins8(v, ix, f.z, gi + 2);
            if ((gi + 3) != pad && (gi + 3) != unk) ins8(v, ix, f.w, gi + 3);
        }
    }

    // ---- merge: wave butterfly, then cross-wave via LDS ----
    wave_merge8(v, ix);
    if (ln == 0) {
#pragma unroll
        for (int k = 0; k < 8; ++k) { s_mv[wv * 8 + k] = v[k]; s_mi[wv * 8 + k] = ix[k]; }
    }
    __syncthreads();
    if (tid == 0) {
        float bv[8]; int bi[8];
#pragma unroll
        for (int k = 0; k < 8; ++k) { bv[k] = -INFINITY; bi[k] = 0x7FFFFFFF; }
        for (int j = 0; j < 32; ++j) ins8(bv, bi, s_mv[j], s_mi[j]);
        float* ov = topv + (size_t)hrow * 8;
        int*   oi = topi + (size_t)hrow * 8;
#pragma unroll
        for (int k = 0; k < 8; ++k) { ov[k] = bv[k]; oi[k] = bi[k]; }
    }
}

// ---------------------------------------------------------------------------
// Phase 2: 16-step beam scan, one wave per batch. Combines half-row partial
// sums into logS, builds 64 candidates/step (4 beams x 2 halves x 8), exact
// top-8 via 64-lane bitonic sort, eos mask, exact top-4 via 8-lane sort.
// Lane order (beam-major, half0 before half1, within-half word-asc on ties)
// makes cj=lane the exact flat-index tie-break.
__global__ __launch_bounds__(64) void phase2_beam_scan(
    const float* __restrict__ topv,
    const int*   __restrict__ topi,
    const float* __restrict__ sums,
    const int*   __restrict__ eos_p,
    float* __restrict__ out)
{
    const int b    = blockIdx.x;   // batch index
    const int lane = threadIdx.x;  // 0..63, single wave
    const int eos  = *eos_p;

    __shared__ float s_v[T_STEPS][64];
    __shared__ int   s_w[T_STEPS][64];
    __shared__ float s_ls[T_STEPS][BEAM];   // combined logS per (t, beam)
    __shared__ float s_sc[BEAM];
    __shared__ int   s_rb[T_STEPS][BEAM];
    __shared__ int   s_rw[T_STEPS][BEAM];

    // Combined log-sum per (t, beam): exactly 64 entries, one per lane.
    {
        const int t = lane >> 2, beam = lane & 3;
        const int r2 = (t * BB + b * BEAM + beam) * 2;
        s_ls[t][beam] = logf(sums[r2] + sums[r2 + 1]);
    }
    __syncthreads();

    // Preload 16 steps x 64 candidates: j = beam*16 + half*8 + pos.
    for (int g = lane; g < T_STEPS * 64; g += 64) {
        const int t = g >> 6, j = g & 63;
        const int beam = j >> 4, half = (j >> 3) & 1, pos = j & 7;
        const size_t off =
            ((size_t)((t * BB + b * BEAM + beam) * 2 + half)) * 8 + pos;
        s_v[t][j] = topv[off] - s_ls[t][beam];
        s_w[t][j] = topi[off];
    }
    if (lane < BEAM) s_sc[lane] = 0.0f;
    __syncthreads();

    for (int t = 0; t < T_STEPS; ++t) {
        int   cj   = lane;                    // candidate id (tie-break key)
        int   word = s_w[t][lane];
        float val  = s_v[t][lane] + s_sc[lane >> 4];

        // ---- 64-lane bitonic sort, descending by (val, cj asc) ----
#pragma unroll
        for (int k = 2; k <= 64; k <<= 1) {
#pragma unroll
            for (int j = k >> 1; j > 0; j >>= 1) {
                const float ov = __shfl_xor(val,  j, 64);
                const int   oc = __shfl_xor(cj,   j, 64);
                const int   ow = __shfl_xor(word, j, 64);
                const bool dirDesc   = ((lane & k) == 0);
                const bool iAmLow    = ((lane & j) == 0);
                const bool mineFirst = gtvi(val, cj, ov, oc);
                const bool takeOther = dirDesc ? (iAmLow ? !mineFirst : mineFirst)
                                               : (iAmLow ? mineFirst : !mineFirst);
                if (takeOther) { val = ov; cj = oc; word = ow; }
            }
        }

        // ---- lanes 0..7 = top-8 desc. eos mask, then exact top_k(masked,4)
        float mval; int pos = lane, srcb = 0, w8 = 0;
        if (lane < 8) {
            w8   = word;
            srcb = cj >> 4;                  // source beam (16 cands/beam)
            const bool iseos = (w8 == eos) && (val > -INFINITY);
            mval = iseos ? -INFINITY : val;
        } else {
            mval = -INFINITY;
        }
#pragma unroll
        for (int k = 2; k <= 8; k <<= 1) {
#pragma unroll
            for (int j = k >> 1; j > 0; j >>= 1) {
                const float ov = __shfl_xor(mval, j, 64);
                const int   op = __shfl_xor(pos,  j, 64);
                const int   ob = __shfl_xor(srcb, j, 64);
                const int   ow = __shfl_xor(w8,   j, 64);
                const bool dirDesc   = ((lane & k) == 0);
                const bool iAmLow    = ((lane & j) == 0);
                const bool mineFirst = gtvi(mval, pos, ov, op);
                const bool takeOther = dirDesc ? (iAmLow ? !mineFirst : mineFirst)
                                               : (iAmLow ? mineFirst : !mineFirst);
                if (takeOther) { mval = ov; pos = op; srcb = ob; w8 = ow; }
            }
        }

        if (lane < 4) {
            s_sc[lane]    = mval;   // new cumulative scores (sel_scores)
            s_rb[t][lane] = srcb;   // source (old) beam
            s_rw[t][lane] = w8;     // chosen word
        }
        __syncthreads();
    }

    // Backtrace + output (d_out = [scores (128) | tokens (128*17)], f32)
    if (lane < BEAM) {
        out[b * BEAM + lane] = s_sc[lane];
        float* tout = out + BATCH * BEAM + (size_t)(b * BEAM + lane) * (T_STEPS + 1);
        int bp = lane;
#pragma unroll
        for (int t = T_STEPS - 1; t >= 0; --t) {
            tout[t + 1] = (float)s_rw[t][bp];
            bp = s_rb[t][bp];
        }
        tout[0] = (float)eos;   // begin token
    }
}

// ---------------------------------------------------------------------------
extern "C" void kernel_launch(void* const* d_in, const int* in_sizes, int n_in,
                              void* d_out, int out_size, void* d_ws, size_t ws_size,
                              hipStream_t stream) {
    const float* logits = (const float*)d_in[0];
    const int*   pad_p  = (const int*)d_in[1];
    const int*   unk_p  = (const int*)d_in[2];
    const int*   eos_p  = (const int*)d_in[3];
    // d_in[4] = beam_size (hardcoded 4 to match shapes)

    // Workspace layout (half-rows = T*BB*2 = 4096):
    //   topv [4096*8] f32 (128 KB) | topi [4096*8] i32 (128 KB) | sums [4096] f32
    const int HR = T_STEPS * BB * 2;
    float* topv = (float*)d_ws;
    int*   topi = (int*)(topv + (size_t)HR * 8);
    float* sums = (float*)(topi + (size_t)HR * 8);

    hipLaunchKernelGGL(phase1_topk_half, dim3(HR), dim3(256), 0, stream,
                       logits, pad_p, unk_p, topv, topi, sums);
    hipLaunchKernelGGL(phase2_beam_scan, dim3(BATCH), dim3(64), 0, stream,
                       topv, topi, sums, eos_p, (float*)d_out);
}

// Round 6
// 114.031 us; speedup vs baseline: 1.0283x; 1.0283x over previous
//
#include <hip/hip_runtime.h>
#include <math.h>

// Problem constants (fixed by the reference's setup_inputs)
#define T_STEPS 16
#define BB      128
#define VOCAB   32000
#define V4      (VOCAB / 4)   // 8000 float4 per row
#define BEAM    4
#define BATCH   (BB / BEAM)   // 32
#define TAU     2.75f         // survivor threshold: E[survivors/row] ~ 96

// ---------------------------------------------------------------------------
// Total-order comparator matching jax.lax.top_k: value descending, index
// ascending on ties. (a ranks before b)?
__device__ __forceinline__ bool gtvi(float av, int ai, float bv, int bi) {
    return (av > bv) || (av == bv && ai < bi);
}

// Insert (x, gi) into a sorted-descending top-8 list (fallback/merge paths).
__device__ __forceinline__ void ins8(float (&v)[8], int (&ix)[8], float x, int gi) {
    if (gtvi(x, gi, v[7], ix[7])) {
        v[7] = x; ix[7] = gi;
#pragma unroll
        for (int j = 7; j > 0; --j) {
            if (gtvi(v[j], ix[j], v[j - 1], ix[j - 1])) {
                float tv = v[j]; v[j] = v[j - 1]; v[j - 1] = tv;
                int   ti = ix[j]; ix[j] = ix[j - 1]; ix[j - 1] = ti;
            }
        }
    }
}

// 19-comparator sorting network (Batcher, n=8), descending under gtvi.
__device__ __forceinline__ void sort8(float (&v)[8], int (&ix)[8]) {
#define CE(a, b)                                                              \
    if (gtvi(v[b], ix[b], v[a], ix[a])) {                                     \
        float tv = v[a]; v[a] = v[b]; v[b] = tv;                              \
        int   ti = ix[a]; ix[a] = ix[b]; ix[b] = ti;                          \
    }
    CE(0,1) CE(2,3) CE(4,5) CE(6,7)
    CE(0,2) CE(1,3) CE(4,6) CE(5,7)
    CE(1,2) CE(5,6) CE(0,4) CE(3,7)
    CE(1,5) CE(2,6)
    CE(1,4) CE(3,6)
    CE(2,4) CE(3,5)
    CE(3,4)
#undef CE
}

// Wave(64)-level butterfly merge of per-lane sorted-desc 8-lists.
__device__ __forceinline__ void wave_merge8(float (&v)[8], int (&ix)[8]) {
#pragma unroll
    for (int m = 1; m < 64; m <<= 1) {
        float u[8]; int ju[8];
#pragma unroll
        for (int k = 0; k < 8; ++k) {
            u[k]  = __shfl_xor(v[k],  m, 64);
            ju[k] = __shfl_xor(ix[k], m, 64);
        }
        float w[8]; int jw[8];
#pragma unroll
        for (int k = 0; k < 8; ++k) {
            if (gtvi(u[7 - k], ju[7 - k], v[k], ix[k])) { w[k] = u[7 - k]; jw[k] = ju[7 - k]; }
            else                                        { w[k] = v[k];     jw[k] = ix[k];     }
        }
#define CE_DESC(a, b)                                                         \
        if (gtvi(w[b], jw[b], w[a], jw[a])) {                                 \
            float tv = w[a]; w[a] = w[b]; w[b] = tv;                          \
            int   ti = jw[a]; jw[a] = jw[b]; jw[b] = ti;                      \
        }
        CE_DESC(0, 4) CE_DESC(1, 5) CE_DESC(2, 6) CE_DESC(3, 7)
        CE_DESC(0, 2) CE_DESC(1, 3) CE_DESC(4, 6) CE_DESC(5, 7)
        CE_DESC(0, 1) CE_DESC(2, 3) CE_DESC(4, 5) CE_DESC(6, 7)
#undef CE_DESC
#pragma unroll
        for (int k = 0; k < 8; ++k) { v[k] = w[k]; ix[k] = jw[k]; }
    }
}

// ---------------------------------------------------------------------------
// Phase 1: per (step,row): sum(exp(x)) + exact top-8 of x excluding pad/unk.
// Hot loop: zero LDS, depth-2 pipeline, cheap unsorted register append for
// the rare (>TAU) survivors. Per-lane lists sorted once after the stream.
// <8 valid survivors or per-lane overflow -> exact full rescan (L2-hot).
__global__ __launch_bounds__(256, 4) void phase1_topk_lsm(
    const float* __restrict__ logits,
    const int*   __restrict__ pad_p,
    const int*   __restrict__ unk_p,
    float* __restrict__ topv,
    int*   __restrict__ topi)
{
    __shared__ float s_red[4];
    __shared__ int   s_icnt[4];
    __shared__ float s_mv[32];
    __shared__ int   s_mi[32];
    __shared__ float s_logS;
    __shared__ int   s_tot;

    const int row = blockIdx.x;            // t*BB + r
    const int tid = threadIdx.x;
    const int pad = *pad_p, unk = *unk_p;
    const float4* __restrict__ src =
        reinterpret_cast<const float4*>(logits + (size_t)row * VOCAB);

    float v[8]; int ix[8];
#pragma unroll
    for (int k = 0; k < 8; ++k) { v[k] = -INFINITY; ix[k] = 0x7FFFFFFF; }
    float tsum = 0.0f;
    int   c = 0, ovf = 0;                  // appended survivors / overflow flag

    auto process = [&](float4 q, int gi) {   // gi = word index of q.x
        tsum += (__expf(q.x) + __expf(q.y)) + (__expf(q.z) + __expf(q.w));
        const float mx = fmaxf(fmaxf(q.x, q.y), fmaxf(q.z, q.w));
        if (__builtin_expect(mx > TAU, 0)) {
            int cnt4 = (q.x > TAU) + (q.y > TAU) + (q.z > TAU) + (q.w > TAU);
            float a0 = q.x, a1 = q.y, a2 = q.z, a3 = q.w;
            do {
                // extract current max, preferring lower component index
                float m0 = a0; int id = 0;
                if (a1 > m0) { m0 = a1; id = 1; }
                if (a2 > m0) { m0 = a2; id = 2; }
                if (a3 > m0) { m0 = a3; id = 3; }
                const int w = gi + id;
                if (w != pad && w != unk) {
                    switch (c) {           // static-index append (no scratch)
                        case 0: v[0] = m0; ix[0] = w; break;
                        case 1: v[1] = m0; ix[1] = w; break;
                        case 2: v[2] = m0; ix[2] = w; break;
                        case 3: v[3] = m0; ix[3] = w; break;
                        case 4: v[4] = m0; ix[4] = w; break;
                        case 5: v[5] = m0; ix[5] = w; break;
                        case 6: v[6] = m0; ix[6] = w; break;
                        case 7: v[7] = m0; ix[7] = w; break;
                        default: ovf = 1; break;
                    }
                    ++c;
                }
                if      (id == 0) a0 = -INFINITY;
                else if (id == 1) a1 = -INFINITY;
                else if (id == 2) a2 = -INFINITY;
                else              a3 = -INFINITY;
            } while (--cnt4 > 0);
        }
    };

    // ---- depth-2 pipelined hot loop: 31 full iters + 64-thread tail ----
    float4 q = src[tid];
    int kv = tid;
    for (int i = 0; i < 30; ++i) {
        float4 qn = src[kv + 256];         // prefetch next (2 loads in flight)
        process(q, kv * 4);
        q = qn; kv += 256;
    }
    process(q, kv * 4);
    if (tid < 64) {
        float4 qt = src[7936 + tid];
        process(qt, (7936 + tid) * 4);
    }

    // ---- block reductions: exp-sum + valid-survivor count (ovf poisons) ----
    int cc = ovf ? -65536 : c;
#pragma unroll
    for (int m = 1; m < 64; m <<= 1) {
        tsum += __shfl_xor(tsum, m, 64);
        cc   += __shfl_xor(cc,   m, 64);
    }
    const int wv = tid >> 6, ln = tid & 63;
    if (ln == 0) { s_red[wv] = tsum; s_icnt[wv] = cc; }
    __syncthreads();
    if (tid == 0) {
        s_logS = logf((s_red[0] + s_red[1]) + (s_red[2] + s_red[3]));
        s_tot  = (s_icnt[0] + s_icnt[1]) + (s_icnt[2] + s_icnt[3]);
    }
    __syncthreads();
    const float logS = s_logS;

    if (s_tot >= 8) {
        sort8(v, ix);                      // unsorted appends -> sorted desc
    } else {
        // ---- exact fallback (never for N(0,1) rows): full rescan ----
#pragma unroll
        for (int k = 0; k < 8; ++k) { v[k] = -INFINITY; ix[k] = 0x7FFFFFFF; }
        for (int k2 = tid; k2 < V4; k2 += 256) {
            float4 f = src[k2];
            const int gi = k2 * 4;
            if ((gi + 0) != pad && (gi + 0) != unk) ins8(v, ix, f.x, gi + 0);
            if ((gi + 1) != pad && (gi + 1) != unk) ins8(v, ix, f.y, gi + 1);
            if ((gi + 2) != pad && (gi + 2) != unk) ins8(v, ix, f.z, gi + 2);
            if ((gi + 3) != pad && (gi + 3) != unk) ins8(v, ix, f.w, gi + 3);
        }
    }

    // ---- merge: wave butterfly, then cross-wave via LDS ----
    wave_merge8(v, ix);
    if (ln == 0) {
#pragma unroll
        for (int k = 0; k < 8; ++k) { s_mv[wv * 8 + k] = v[k]; s_mi[wv * 8 + k] = ix[k]; }
    }
    __syncthreads();
    if (tid == 0) {
        float bv[8]; int bi[8];
#pragma unroll
        for (int k = 0; k < 8; ++k) { bv[k] = -INFINITY; bi[k] = 0x7FFFFFFF; }
        for (int j = 0; j < 32; ++j) ins8(bv, bi, s_mv[j], s_mi[j]);
        float* ov = topv + (size_t)row * 8;
        int*   oi = topi + (size_t)row * 8;
#pragma unroll
        for (int k = 0; k < 8; ++k) { ov[k] = bv[k] - logS; oi[k] = bi[k]; }
    }
}

// ---------------------------------------------------------------------------
// Phase 2: 16-step beam scan, one wave per batch, fully wave-parallel.
// All candidates preloaded to LDS once; per step a 64-lane bitonic sort by
// (val desc, cand-idx asc) gives the exact top-8, then an 8-lane mini-sort
// after eos masking gives the exact top_k(masked, 4).
__global__ __launch_bounds__(64) void phase2_beam_scan(
    const float* __restrict__ topv,
    const int*   __restrict__ topi,
    const int*   __restrict__ eos_p,
    float* __restrict__ out)
{
    const int b    = blockIdx.x;   // batch index
    const int lane = threadIdx.x;  // 0..63, single wave
    const int eos  = *eos_p;

    __shared__ float s_v[T_STEPS][32];
    __shared__ int   s_w[T_STEPS][32];
    __shared__ float s_sc[BEAM];
    __shared__ int   s_rb[T_STEPS][BEAM];
    __shared__ int   s_rw[T_STEPS][BEAM];

    for (int g = lane; g < T_STEPS * 32; g += 64) {
        const int t = g >> 5, j = g & 31;
        const size_t off = (size_t)t * (BB * 8) + (size_t)b * (BEAM * 8) + j;
        s_v[t][j] = topv[off];
        s_w[t][j] = topi[off];
    }
    if (lane < BEAM) s_sc[lane] = 0.0f;
    __syncthreads();

    for (int t = 0; t < T_STEPS; ++t) {
        float val; int word, cj;
        if (lane < 32) {
            cj   = lane;                       // beam*8 + pos
            word = s_w[t][lane];
            val  = s_v[t][lane] + s_sc[lane >> 3];
        } else {
            cj = 64 + lane; word = 0; val = -INFINITY;
        }

        // ---- 64-lane bitonic sort, descending by (val, cj asc) ----
#pragma unroll
        for (int k = 2; k <= 64; k <<= 1) {
#pragma unroll
            for (int j = k >> 1; j > 0; j >>= 1) {
                const float ov = __shfl_xor(val,  j, 64);
                const int   oc = __shfl_xor(cj,   j, 64);
                const int   ow = __shfl_xor(word, j, 64);
                const bool dirDesc   = ((lane & k) == 0);
                const bool iAmLow    = ((lane & j) == 0);
                const bool mineFirst = gtvi(val, cj, ov, oc);
                const bool takeOther = dirDesc ? (iAmLow ? !mineFirst : mineFirst)
                                               : (iAmLow ? mineFirst : !mineFirst);
                if (takeOther) { val = ov; cj = oc; word = ow; }
            }
        }

        // ---- lanes 0..7 = top-8 desc. eos mask, then exact top_k(masked,4)
        float mval; int pos = lane, srcb = 0, w8 = 0;
        if (lane < 8) {
            w8   = word;
            srcb = cj >> 3;
            const bool iseos = (w8 == eos) && (val > -INFINITY);
            mval = iseos ? -INFINITY : val;
        } else {
            mval = -INFINITY;
        }
#pragma unroll
        for (int k = 2; k <= 8; k <<= 1) {
#pragma unroll
            for (int j = k >> 1; j > 0; j >>= 1) {
                const float ov = __shfl_xor(mval, j, 64);
                const int   op = __shfl_xor(pos,  j, 64);
                const int   ob = __shfl_xor(srcb, j, 64);
                const int   ow = __shfl_xor(w8,   j, 64);
                const bool dirDesc   = ((lane & k) == 0);
                const bool iAmLow    = ((lane & j) == 0);
                const bool mineFirst = gtvi(mval, pos, ov, op);
                const bool takeOther = dirDesc ? (iAmLow ? !mineFirst : mineFirst)
                                               : (iAmLow ? mineFirst : !mineFirst);
                if (takeOther) { mval = ov; pos = op; srcb = ob; w8 = ow; }
            }
        }

        if (lane < 4) {
            s_sc[lane]    = mval;   // new cumulative scores (sel_scores)
            s_rb[t][lane] = srcb;   // source (old) beam
            s_rw[t][lane] = w8;     // chosen word
        }
        __syncthreads();
    }

    // Backtrace + output (d_out = [scores (128) | tokens (128*17)], f32)
    if (lane < BEAM) {
        out[b * BEAM + lane] = s_sc[lane];
        float* tout = out + BATCH * BEAM + (size_t)(b * BEAM + lane) * (T_STEPS + 1);
        int bp = lane;
#pragma unroll
        for (int t = T_STEPS - 1; t >= 0; --t) {
            tout[t + 1] = (float)s_rw[t][bp];
            bp = s_rb[t][bp];
        }
        tout[0] = (float)eos;   // begin token
    }
}

// ---------------------------------------------------------------------------
extern "C" void kernel_launch(void* const* d_in, const int* in_sizes, int n_in,
                              void* d_out, int out_size, void* d_ws, size_t ws_size,
                              hipStream_t stream) {
    const float* logits = (const float*)d_in[0];
    const int*   pad_p  = (const int*)d_in[1];
    const int*   unk_p  = (const int*)d_in[2];
    const int*   eos_p  = (const int*)d_in[3];
    // d_in[4] = beam_size (hardcoded 4 to match shapes)

    // Workspace: topv [T*BB*8] f32, then topi [T*BB*8] i32  (128 KB total)
    float* topv = (float*)d_ws;
    int*   topi = (int*)(topv + T_STEPS * BB * 8);

    hipLaunchKernelGGL(phase1_topk_lsm, dim3(T_STEPS * BB), dim3(256), 0, stream,
                       logits, pad_p, unk_p, topv, topi);
    hipLaunchKernelGGL(phase2_beam_scan, dim3(BATCH), dim3(64), 0, stream,
                       topv, topi, eos_p, (float*)d_out);
}